// Round 16
// baseline (611.558 us; speedup 1.0000x reference)
//
#include <hip/hip_runtime.h>
#include <math.h>

// ---------------------------------------------------------------------------
// GCN pipeline: conv1(relu) -> conv2(relu) -> quantize(+reg) -> add -> conv3
// GEMMs: split-bf16 MFMA (Ootomo 3-term), pre-split hi/lo tables, register
// prefetch + LDS-transposed epilogue, XCD-chunk-swizzled grid. Quantize:
// VALU register-GEMM, full-K=64 single-barrier schedule (v10): one staging
// pass (As+Bs 70KB), 1 barrier, 64 straight FMA iters, 1 barrier, flush.
// ---------------------------------------------------------------------------

typedef short bf16x8 __attribute__((ext_vector_type(8)));
typedef float f32x4 __attribute__((ext_vector_type(4)));

__device__ __forceinline__ unsigned short bf16_rne(float a) {
    unsigned u = __builtin_bit_cast(unsigned, a);
    return (unsigned short)((u + 0x7FFFu + ((u >> 16) & 1u)) >> 16);
}
__device__ __forceinline__ float bf16_to_f(unsigned short h) {
    return __builtin_bit_cast(float, (unsigned)h << 16);
}
__device__ __forceinline__ void split4(const float* e, unsigned short* h, unsigned short* l) {
#pragma unroll
    for (int t = 0; t < 4; ++t) {
        h[t] = bf16_rne(e[t]);
        l[t] = bf16_rne(e[t] - bf16_to_f(h[t]));
    }
}

// ---------------- CSR build ----------------

__global__ void k_init(int* cnt, int* cursor, int* counter, float* balance, int n) {
    int i = blockIdx.x * blockDim.x + threadIdx.x;
    if (i < n) { cnt[i] = 0; cursor[i] = 0; }
    if (i < 480) balance[i] = 0.f;
    if (i == 0) *counter = 0;
}

__global__ void k_count(const int* __restrict__ dst, int* __restrict__ cnt, int e) {
    int i = blockIdx.x * blockDim.x + threadIdx.x;
    if (i < e) atomicAdd(&cnt[dst[i]], 1);
}

__global__ void k_allocdinv(const int* __restrict__ cnt, int* __restrict__ row_start,
                            int* __restrict__ counter, float* __restrict__ dinv, int n) {
    int i = blockIdx.x * blockDim.x + threadIdx.x;
    if (i < n) {
        row_start[i] = atomicAdd(counter, cnt[i]);
        dinv[i] = rsqrtf((float)cnt[i] + 1.0f);   // +1 self loop
    }
}

__global__ void k_fill(const int* __restrict__ src, const int* __restrict__ dst,
                       const float* __restrict__ dinv, const int* __restrict__ row_start,
                       int* __restrict__ cursor, int* __restrict__ csr_src,
                       float* __restrict__ csr_norm, int e) {
    int i = blockIdx.x * blockDim.x + threadIdx.x;
    if (i >= e) return;
    int s = src[i], d = dst[i];
    int slot = atomicAdd(&cursor[d], 1);
    int idx = row_start[d] + slot;
    csr_src[idx] = s;
    csr_norm[idx] = dinv[s] * dinv[d];
}

// ---------------- fused split kernel ----------------

__global__ void k_splitfused(const float* __restrict__ X, short* __restrict__ Xh,
                             short* __restrict__ Xl, int total8,
                             const float* __restrict__ W0, const float* __restrict__ W1,
                             const float* __restrict__ W2,
                             short* __restrict__ w0h, short* __restrict__ w0l,
                             short* __restrict__ w1h, short* __restrict__ w1l,
                             short* __restrict__ w2h, short* __restrict__ w2l) {
    int i = blockIdx.x * blockDim.x + threadIdx.x;
    if (i < total8) {
        float4 a = *(const float4*)(X + (size_t)i * 8);
        float4 b = *(const float4*)(X + (size_t)i * 8 + 4);
        float e0[4] = {a.x, a.y, a.z, a.w}, e1[4] = {b.x, b.y, b.z, b.w};
        unsigned short h0[4], l0[4], h1[4], l1[4];
        split4(e0, h0, l0);
        split4(e1, h1, l1);
        *(uint4*)(Xh + (size_t)i * 8) = make_uint4(h0[0] | (h0[1] << 16), h0[2] | (h0[3] << 16),
                                                  h1[0] | (h1[1] << 16), h1[2] | (h1[3] << 16));
        *(uint4*)(Xl + (size_t)i * 8) = make_uint4(l0[0] | (l0[1] << 16), l0[2] | (l0[3] << 16),
                                                  l1[0] | (l1[1] << 16), l1[2] | (l1[3] << 16));
        return;
    }
    int k = i - total8;
    if (k >= 163840) return;
    float v;
    short *ph, *pl;
    int j;
    if (k < 65536) {
        j = k; v = W0[(j & 255) * 256 + (j >> 8)]; ph = w0h; pl = w0l;
    } else if (k < 131072) {
        j = k - 65536; v = W1[(j & 255) * 256 + (j >> 8)]; ph = w1h; pl = w1l;
    } else {
        j = k - 131072; v = W2[(j & 255) * 128 + (j >> 8)]; ph = w2h; pl = w2l;
    }
    unsigned short h = bf16_rne(v);
    ph[j] = (short)h;
    pl[j] = (short)bf16_rne(v - bf16_to_f(h));
}

// ---------------- bf16-split MFMA GEMM (XCD-chunk swizzled) ----------------

__global__ __launch_bounds__(256, 2) void k_gemm_bf16s(const short* __restrict__ Ah,
                                                       const short* __restrict__ Al,
                                                       const short* __restrict__ Bh,
                                                       const short* __restrict__ Bl,
                                                       float* __restrict__ C,
                                                       int M, int N, int nbn,
                                                       int q, int r) {
    const int s = blockIdx.x;
    const int xcd = s & 7, jj = s >> 3;
    const int w = (xcd < r ? xcd * (q + 1) : r * (q + 1) + (xcd - r) * q) + jj;
    const int bm = (w / nbn) * 128;
    const int bn = (w % nbn) * 128;

    __shared__ short smem[4 * 128 * 56];
    short* Ash = smem;
    short* Asl = smem + 7168;
    short* Bsh = smem + 14336;
    short* Bsl = smem + 21504;
    const int tid = threadIdx.x;
    const int wave = tid >> 6, lane = tid & 63;
    const int wr = wave >> 1, wc = wave & 1;
    const int lr = lane & 15, lk = lane >> 4;

    int srow[2], ssg[2];
    bool aval[2];
#pragma unroll
    for (int it = 0; it < 2; ++it) {
        int u = it * 256 + tid;
        srow[it] = u >> 2;
        ssg[it] = (u & 3) << 3;
        aval[it] = (bm + srow[it]) < M;
    }

    const bf16x8 z8 = {0, 0, 0, 0, 0, 0, 0, 0};
    bf16x8 pah[2], pal[2], pbh[2], pbl[2];

    auto prefetch = [&](int k0) {
#pragma unroll
        for (int it = 0; it < 2; ++it) {
            size_t arow = (size_t)(bm + srow[it]) * 256 + k0 + ssg[it];
            size_t brow = (size_t)(bn + srow[it]) * 256 + k0 + ssg[it];
            pah[it] = aval[it] ? *(const bf16x8*)(Ah + arow) : z8;
            pal[it] = aval[it] ? *(const bf16x8*)(Al + arow) : z8;
            pbh[it] = *(const bf16x8*)(Bh + brow);
            pbl[it] = *(const bf16x8*)(Bl + brow);
        }
    };

    f32x4 acc[4][4] = {};
    prefetch(0);

    for (int k0 = 0; k0 < 256; k0 += 32) {
#pragma unroll
        for (int it = 0; it < 2; ++it) {
            int off = srow[it] * 56 + ssg[it];
            *(bf16x8*)&Ash[off] = pah[it];
            *(bf16x8*)&Asl[off] = pal[it];
            *(bf16x8*)&Bsh[off] = pbh[it];
            *(bf16x8*)&Bsl[off] = pbl[it];
        }
        __syncthreads();

        bf16x8 ah[4], al[4], bh[4], bl[4];
#pragma unroll
        for (int i = 0; i < 4; ++i) {
            int off = (wr * 64 + i * 16 + lr) * 56 + lk * 8;
            ah[i] = *(bf16x8*)&Ash[off];
            al[i] = *(bf16x8*)&Asl[off];
        }
#pragma unroll
        for (int j = 0; j < 4; ++j) {
            int off = (wc * 64 + j * 16 + lr) * 56 + lk * 8;
            bh[j] = *(bf16x8*)&Bsh[off];
            bl[j] = *(bf16x8*)&Bsl[off];
        }

        if (k0 < 224) prefetch(k0 + 32);

#pragma unroll
        for (int i = 0; i < 4; ++i)
#pragma unroll
            for (int j = 0; j < 4; ++j) {
                acc[i][j] = __builtin_amdgcn_mfma_f32_16x16x32_bf16(al[i], bh[j], acc[i][j], 0, 0, 0);
                acc[i][j] = __builtin_amdgcn_mfma_f32_16x16x32_bf16(ah[i], bl[j], acc[i][j], 0, 0, 0);
                acc[i][j] = __builtin_amdgcn_mfma_f32_16x16x32_bf16(ah[i], bh[j], acc[i][j], 0, 0, 0);
            }
        __syncthreads();
    }

    float* Cs = (float*)smem;
#pragma unroll
    for (int p = 0; p < 2; ++p) {
        if (wc == p) {
#pragma unroll
            for (int i = 0; i < 4; ++i)
#pragma unroll
                for (int r2 = 0; r2 < 4; ++r2) {
                    int row = wr * 64 + i * 16 + lk * 4 + r2;
#pragma unroll
                    for (int j = 0; j < 4; ++j)
                        Cs[row * 68 + j * 16 + lr] = acc[i][j][r2];
                }
        }
        __syncthreads();
#pragma unroll
        for (int t = 0; t < 8; ++t) {
            int idx = t * 256 + tid;
            int row = idx >> 4, c4 = idx & 15;
            if (bm + row < M)
                *(float4*)(C + (size_t)(bm + row) * N + bn + p * 64 + c4 * 4) =
                    *(const float4*)&Cs[row * 68 + c4 * 4];
        }
        __syncthreads();
    }
}

// ---------------- Aggregation (gather over CSR), one wave per node ----------------
// L3-BW-bound floor ~125us. MODE=1 emits bf16 hi/lo split.

template <bool RELU, int MODE>
__global__ __launch_bounds__(256, 4) void k_agg4(const float* __restrict__ xw,
                                                 const float* __restrict__ dinv,
                                                 const int* __restrict__ csr_src,
                                                 const float* __restrict__ csr_norm,
                                                 const int* __restrict__ row_start,
                                                 const int* __restrict__ cnt,
                                                 const float* __restrict__ bias,
                                                 float* __restrict__ out,
                                                 short* __restrict__ outH,
                                                 short* __restrict__ outL, int n) {
    int node = blockIdx.x * 4 + (threadIdx.x >> 6);
    if (node >= n) return;
    int lane = threadIdx.x & 63;
    int c = lane * 4;
    float di = dinv[node];
    float4 self = *(const float4*)(xw + (size_t)node * 256 + c);
    float4 bv = *(const float4*)(bias + c);
    float sw = di * di;
    float ax = self.x * sw + bv.x;
    float ay = self.y * sw + bv.y;
    float az = self.z * sw + bv.z;
    float aw = self.w * sw + bv.w;
    int st = row_start[node];
    int m = cnt[node];
    for (int t0 = 0; t0 < m; t0 += 64) {
        int rem = m - t0;
        int cnt_i = rem < 64 ? rem : 64;
        int idx_l = 0;
        float nrm_l = 0.f;
        if (lane < cnt_i) {
            idx_l = csr_src[st + t0 + lane];
            nrm_l = csr_norm[st + t0 + lane];
        }
        int t = 0;
        for (; t + 8 <= cnt_i; t += 8) {
            const float* p0 = xw + (size_t)__shfl(idx_l, t + 0, 64) * 256 + c;
            const float* p1 = xw + (size_t)__shfl(idx_l, t + 1, 64) * 256 + c;
            const float* p2 = xw + (size_t)__shfl(idx_l, t + 2, 64) * 256 + c;
            const float* p3 = xw + (size_t)__shfl(idx_l, t + 3, 64) * 256 + c;
            const float* p4 = xw + (size_t)__shfl(idx_l, t + 4, 64) * 256 + c;
            const float* p5 = xw + (size_t)__shfl(idx_l, t + 5, 64) * 256 + c;
            const float* p6 = xw + (size_t)__shfl(idx_l, t + 6, 64) * 256 + c;
            const float* p7 = xw + (size_t)__shfl(idx_l, t + 7, 64) * 256 + c;
            float4 v0 = *(const float4*)p0;
            float4 v1 = *(const float4*)p1;
            float4 v2 = *(const float4*)p2;
            float4 v3 = *(const float4*)p3;
            float4 v4 = *(const float4*)p4;
            float4 v5 = *(const float4*)p5;
            float4 v6 = *(const float4*)p6;
            float4 v7 = *(const float4*)p7;
            float w0 = __shfl(nrm_l, t + 0, 64);
            float w1 = __shfl(nrm_l, t + 1, 64);
            float w2 = __shfl(nrm_l, t + 2, 64);
            float w3 = __shfl(nrm_l, t + 3, 64);
            float w4 = __shfl(nrm_l, t + 4, 64);
            float w5 = __shfl(nrm_l, t + 5, 64);
            float w6 = __shfl(nrm_l, t + 6, 64);
            float w7 = __shfl(nrm_l, t + 7, 64);
            ax += v0.x * w0; ay += v0.y * w0; az += v0.z * w0; aw += v0.w * w0;
            ax += v1.x * w1; ay += v1.y * w1; az += v1.z * w1; aw += v1.w * w1;
            ax += v2.x * w2; ay += v2.y * w2; az += v2.z * w2; aw += v2.w * w2;
            ax += v3.x * w3; ay += v3.y * w3; az += v3.z * w3; aw += v3.w * w3;
            ax += v4.x * w4; ay += v4.y * w4; az += v4.z * w4; aw += v4.w * w4;
            ax += v5.x * w5; ay += v5.y * w5; az += v5.z * w5; aw += v5.w * w5;
            ax += v6.x * w6; ay += v6.y * w6; az += v6.z * w6; aw += v6.w * w6;
            ax += v7.x * w7; ay += v7.y * w7; az += v7.z * w7; aw += v7.w * w7;
        }
        for (; t < cnt_i; ++t) {
            int s = __shfl(idx_l, t, 64);
            float w = __shfl(nrm_l, t, 64);
            float4 v = *(const float4*)(xw + (size_t)s * 256 + c);
            ax += v.x * w; ay += v.y * w; az += v.z * w; aw += v.w * w;
        }
    }
    if (RELU) {
        ax = ax > 0.f ? ax : 0.5f * ax;
        ay = ay > 0.f ? ay : 0.5f * ay;
        az = az > 0.f ? az : 0.5f * az;
        aw = aw > 0.f ? aw : 0.5f * aw;
    }
    if (MODE == 0) {
        *(float4*)(out + (size_t)node * 256 + c) = make_float4(ax, ay, az, aw);
    } else {
        float e[4] = {ax, ay, az, aw};
        unsigned short h[4], l[4];
        split4(e, h, l);
        size_t o = (size_t)node * 256 + c;
        *(uint2*)(outH + o) = make_uint2(h[0] | (h[1] << 16), h[2] | (h[3] << 16));
        *(uint2*)(outL + o) = make_uint2(l[0] | (l[1] << 16), l[2] | (l[3] << 16));
    }
}

__global__ __launch_bounds__(256, 4) void k_agg2(const float* __restrict__ xw,
                                                 const float* __restrict__ dinv,
                                                 const int* __restrict__ csr_src,
                                                 const float* __restrict__ csr_norm,
                                                 const int* __restrict__ row_start,
                                                 const int* __restrict__ cnt,
                                                 const float* __restrict__ bias,
                                                 float* __restrict__ out, int n) {
    int node = blockIdx.x * 4 + (threadIdx.x >> 6);
    if (node >= n) return;
    int lane = threadIdx.x & 63;
    int c = lane * 2;
    float di = dinv[node];
    float2 self = *(const float2*)(xw + (size_t)node * 128 + c);
    float2 bv = *(const float2*)(bias + c);
    float sw = di * di;
    float ax = self.x * sw + bv.x;
    float ay = self.y * sw + bv.y;
    int st = row_start[node];
    int m = cnt[node];
    for (int t0 = 0; t0 < m; t0 += 64) {
        int rem = m - t0;
        int cnt_i = rem < 64 ? rem : 64;
        int idx_l = 0;
        float nrm_l = 0.f;
        if (lane < cnt_i) {
            idx_l = csr_src[st + t0 + lane];
            nrm_l = csr_norm[st + t0 + lane];
        }
        int t = 0;
        for (; t + 8 <= cnt_i; t += 8) {
            const float* p0 = xw + (size_t)__shfl(idx_l, t + 0, 64) * 128 + c;
            const float* p1 = xw + (size_t)__shfl(idx_l, t + 1, 64) * 128 + c;
            const float* p2 = xw + (size_t)__shfl(idx_l, t + 2, 64) * 128 + c;
            const float* p3 = xw + (size_t)__shfl(idx_l, t + 3, 64) * 128 + c;
            const float* p4 = xw + (size_t)__shfl(idx_l, t + 4, 64) * 128 + c;
            const float* p5 = xw + (size_t)__shfl(idx_l, t + 5, 64) * 128 + c;
            const float* p6 = xw + (size_t)__shfl(idx_l, t + 6, 64) * 128 + c;
            const float* p7 = xw + (size_t)__shfl(idx_l, t + 7, 64) * 128 + c;
            float2 v0 = *(const float2*)p0;
            float2 v1 = *(const float2*)p1;
            float2 v2 = *(const float2*)p2;
            float2 v3 = *(const float2*)p3;
            float2 v4 = *(const float2*)p4;
            float2 v5 = *(const float2*)p5;
            float2 v6 = *(const float2*)p6;
            float2 v7 = *(const float2*)p7;
            float w0 = __shfl(nrm_l, t + 0, 64);
            float w1 = __shfl(nrm_l, t + 1, 64);
            float w2 = __shfl(nrm_l, t + 2, 64);
            float w3 = __shfl(nrm_l, t + 3, 64);
            float w4 = __shfl(nrm_l, t + 4, 64);
            float w5 = __shfl(nrm_l, t + 5, 64);
            float w6 = __shfl(nrm_l, t + 6, 64);
            float w7 = __shfl(nrm_l, t + 7, 64);
            ax += v0.x * w0; ay += v0.y * w0;
            ax += v1.x * w1; ay += v1.y * w1;
            ax += v2.x * w2; ay += v2.y * w2;
            ax += v3.x * w3; ay += v3.y * w3;
            ax += v4.x * w4; ay += v4.y * w4;
            ax += v5.x * w5; ay += v5.y * w5;
            ax += v6.x * w6; ay += v6.y * w6;
            ax += v7.x * w7; ay += v7.y * w7;
        }
        for (; t < cnt_i; ++t) {
            int s = __shfl(idx_l, t, 64);
            float w = __shfl(nrm_l, t, 64);
            float2 v = *(const float2*)(xw + (size_t)s * 128 + c);
            ax += v.x * w; ay += v.y * w;
        }
    }
    *(float2*)(out + (size_t)node * 128 + c) = make_float2(ax, ay);
}

// ---------------- Quantize v10 (full-K single-barrier register GEMM) ----------
// Same math/order as proven quant4 (k=0..63 sequential -> bit-identical acc).
// Full As[64][132] + Bs[64][132] staged once (70KB, 2 blk/CU): 1 barrier, 64
// uninterrupted FMA iters, softmax in regs, 1 barrier, flush. Removes the
// 2-chunk lockstep (3 barriers + double cent staging) that held quant4 at
// ~105us vs its ~50us VALU+DS floor.

__global__ __launch_bounds__(256, 2) void k_quant10(const float* __restrict__ h2,
                                                    const float* __restrict__ cent,
                                                    short* __restrict__ h3h,
                                                    short* __restrict__ h3l,
                                                    float* __restrict__ balance_g, int n) {
    __shared__ float As[64 * 132];     // As[k][node]
    __shared__ float Bs[64 * 132];     // Bs[k][swizzled cent col]
    __shared__ float bal4[4 * 128];
    __shared__ int km_ls[128 * 4];
    const int tid = threadIdx.x;
    const int n0 = blockIdx.x * 128;
    const int d = blockIdx.y;
    const int ty = tid >> 4, tx = tid & 15;
    const int wave = tid >> 6, lane = tid & 63;

    int gid, base, sz;
    if (tx == 0)       { gid = 0; base = 0;  sz = 1; }
    else if (tx <= 2)  { gid = 1; base = 1;  sz = 2; }
    else if (tx <= 6)  { gid = 2; base = 3;  sz = 4; }
    else if (tx <= 14) { gid = 3; base = 7;  sz = 8; }
    else               { gid = 0; base = 15; sz = 0; }
    const int l = tx - base;
    const int segbase = lane & 48;

    // zero swizzled pad columns (cents 120..127 -> cols 60..63 / 124..127), all 64 k
    for (int idx = tid; idx < 512; idx += 256) {
        int k = idx >> 3, r = idx & 7;
        int col = (r < 4) ? (60 + r) : (120 + r);
        Bs[k * 132 + col] = 0.f;
    }

    // stage As: 128 rows x 64 k = 2048 float4 (8/thread)
#pragma unroll
    for (int it = 0; it < 8; ++it) {
        int q = it * 256 + tid;
        int row = q >> 4, k4 = q & 15;
        float4 v = make_float4(0.f, 0.f, 0.f, 0.f);
        if (n0 + row < n)
            v = *(const float4*)(h2 + (size_t)(n0 + row) * 256 + d * 64 + k4 * 4);
        As[(k4 * 4 + 0) * 132 + row] = v.x;
        As[(k4 * 4 + 1) * 132 + row] = v.y;
        As[(k4 * 4 + 2) * 132 + row] = v.z;
        As[(k4 * 4 + 3) * 132 + row] = v.w;
    }
    // stage Bs: 120 cents x 64 k = 1920 float4, swizzled cols (once, not twice)
#pragma unroll
    for (int it = 0; it < 8; ++it) {
        int q = it * 256 + tid;
        if (q < 1920) {
            int cc = q >> 4, k4 = q & 15;
            float4 v = *(const float4*)(cent + (size_t)cc * 256 + d * 64 + k4 * 4);
            int col = ((cc >> 3) << 2) + (((cc >> 2) & 1) << 6) + (cc & 3);
            Bs[(k4 * 4 + 0) * 132 + col] = v.x;
            Bs[(k4 * 4 + 1) * 132 + col] = v.y;
            Bs[(k4 * 4 + 2) * 132 + col] = v.z;
            Bs[(k4 * 4 + 3) * 132 + col] = v.w;
        }
    }
    __syncthreads();   // the ONLY pre-FMA barrier

    float acc[8][8] = {};
#pragma unroll 4
    for (int k = 0; k < 64; ++k) {
        float4 a0 = *(const float4*)&As[k * 132 + ty * 8];
        float4 a1 = *(const float4*)&As[k * 132 + ty * 8 + 4];
        float4 b0 = *(const float4*)&Bs[k * 132 + tx * 4];
        float4 b1 = *(const float4*)&Bs[k * 132 + 64 + tx * 4];
        float av[8] = {a0.x, a0.y, a0.z, a0.w, a1.x, a1.y, a1.z, a1.w};
        float bv[8] = {b0.x, b0.y, b0.z, b0.w, b1.x, b1.y, b1.z, b1.w};
#pragma unroll
        for (int i = 0; i < 8; ++i)
#pragma unroll
            for (int j = 0; j < 8; ++j)
                acc[i][j] += av[i] * bv[j];
    }

    // ---- per-group softmax/argmax/balance in registers (unchanged) ----
    float balp[8] = {};
#pragma unroll
    for (int i = 0; i < 8; ++i) {
        const int node = ty * 8 + i;
        const bool act = (n0 + node) < n;
        float m = acc[i][0];
        int am = tx * 8;
#pragma unroll
        for (int j = 1; j < 8; ++j)
            if (acc[i][j] > m) { m = acc[i][j]; am = tx * 8 + j; }
#pragma unroll
        for (int s = 1; s <= 4; s <<= 1) {
            int pl = l ^ s;
            int srcl = segbase + base + pl;
            float mo = __shfl(m, srcl, 64);
            int amo = __shfl(am, srcl, 64);
            if (pl < sz && (mo > m || (mo == m && amo < am))) { m = mo; am = amo; }
        }
        float Z = 0.f;
#pragma unroll
        for (int j = 0; j < 8; ++j) {
            float e2 = expf(acc[i][j] - m);
            acc[i][j] = e2;
            Z += e2;
        }
#pragma unroll
        for (int s = 1; s <= 4; s <<= 1) {
            int pl = l ^ s;
            int srcl = segbase + base + pl;
            float Zo = __shfl(Z, srcl, 64);
            if (pl < sz) Z += Zo;
        }
        float invZ = (act && sz > 0) ? (1.0f / Z) : 0.f;
#pragma unroll
        for (int j = 0; j < 8; ++j) balp[j] += acc[i][j] * invZ;
        if (l == 0 && sz > 0) km_ls[node * 4 + gid] = am;
    }

#pragma unroll
    for (int j = 0; j < 8; ++j) {
        float v = balp[j];
        v += __shfl_xor(v, 16, 64);
        v += __shfl_xor(v, 32, 64);
        balp[j] = v;
    }
    if (lane < 16) {
#pragma unroll
        for (int j = 0; j < 8; ++j)
            bal4[wave * 128 + tx * 8 + j] = balp[j];
    }
    __syncthreads();   // the ONLY post-FMA barrier (covers bal4 + km_ls)
    if (tid < 120) {
        float s = bal4[tid] + bal4[128 + tid] + bal4[256 + tid] + bal4[384 + tid];
        atomicAdd(&balance_g[tid * 4 + d], s);
    }

    // ---- P4: h3 = h2 + max_j cent[km_j], bf16 hi/lo emission ----
    {
        const int node = tid >> 1;
        const int half = tid & 1;
        if (n0 + node < n) {
            int k0 = km_ls[node * 4 + 0], k1 = km_ls[node * 4 + 1];
            int k2 = km_ls[node * 4 + 2], k3 = km_ls[node * 4 + 3];
            const float* hp = h2 + (size_t)(n0 + node) * 256 + d * 64 + half * 32;
            const float* c0 = cent + (size_t)k0 * 256 + d * 64 + half * 32;
            const float* c1 = cent + (size_t)k1 * 256 + d * 64 + half * 32;
            const float* c2 = cent + (size_t)k2 * 256 + d * 64 + half * 32;
            const float* c3 = cent + (size_t)k3 * 256 + d * 64 + half * 32;
            size_t obase = (size_t)(n0 + node) * 256 + d * 64 + half * 32;
#pragma unroll
            for (int q = 0; q < 8; ++q) {
                int g = q * 4;
                float4 hv = *(const float4*)(hp + g);
                float4 v0 = *(const float4*)(c0 + g);
                float4 v1 = *(const float4*)(c1 + g);
                float4 v2 = *(const float4*)(c2 + g);
                float4 v3 = *(const float4*)(c3 + g);
                float e[4];
                e[0] = hv.x + fmaxf(fmaxf(v0.x, v1.x), fmaxf(v2.x, v3.x));
                e[1] = hv.y + fmaxf(fmaxf(v0.y, v1.y), fmaxf(v2.y, v3.y));
                e[2] = hv.z + fmaxf(fmaxf(v0.z, v1.z), fmaxf(v2.z, v3.z));
                e[3] = hv.w + fmaxf(fmaxf(v0.w, v1.w), fmaxf(v2.w, v3.w));
                unsigned short h[4], l2[4];
                split4(e, h, l2);
                *(uint2*)(h3h + obase + g) = make_uint2(h[0] | (h[1] << 16), h[2] | (h[3] << 16));
                *(uint2*)(h3l + obase + g) = make_uint2(l2[0] | (l2[1] << 16), l2[2] | (l2[3] << 16));
            }
        }
    }
}

__global__ void k_reg(const float* __restrict__ balance_g, float* __restrict__ out_reg,
                      float inv_n) {
    __shared__ float red[512];
    int tid = threadIdx.x;
    float v = 0.f;
    if (tid < 480) {
        int k = tid >> 2;
        float target = (k < 8) ? 0.125f : (k < 24) ? 0.0625f : (k < 56) ? 0.03125f : 0.015625f;
        float b = balance_g[tid] * inv_n;
        float df = b - target;
        v = df * df;
    }
    red[tid] = v;
    __syncthreads();
    for (int s = 256; s > 0; s >>= 1) {
        if (tid < s) red[tid] += red[tid + s];
        __syncthreads();
    }
    if (tid == 0) *out_reg = sqrtf(red[0]);
}

// ---------------- host launch ----------------

extern "C" void kernel_launch(void* const* d_in, const int* in_sizes, int n_in,
                              void* d_out, int out_size, void* d_ws, size_t ws_size,
                              hipStream_t stream) {
    const float* x    = (const float*)d_in[0];
    const int*   ei   = (const int*)d_in[1];
    const float* W0   = (const float*)d_in[2];
    const float* b0   = (const float*)d_in[3];
    const float* W1   = (const float*)d_in[4];
    const float* b1   = (const float*)d_in[5];
    const float* W2   = (const float*)d_in[6];
    const float* b2   = (const float*)d_in[7];
    const float* cent = (const float*)d_in[8];
    const int n = in_sizes[0] / 256;
    const int e = in_sizes[1] / 2;
    const int* src = ei;
    const int* dst = ei + e;
    float* out = (float*)d_out;

    char* w = (char*)d_ws;
    float* bufA = (float*)w;      w += (size_t)n * 256 * 4;
    float* bufB = (float*)w;      w += (size_t)n * 256 * 4;
    float* dinv = (float*)w;      w += (size_t)n * 4;
    int* cnt = (int*)w;           w += (size_t)n * 4;
    int* row_start = (int*)w;     w += (size_t)n * 4;
    int* cursor = (int*)w;        w += (size_t)n * 4;
    int* csr_src = (int*)w;       w += (size_t)e * 4;
    float* csr_norm = (float*)w;  w += (size_t)e * 4;
    int* counter = (int*)w;       w += 256;
    float* balance = (float*)w;   w += 480 * 4;
    short* w0h = (short*)w;       w += 256 * 256 * 2;
    short* w0l = (short*)w;       w += 256 * 256 * 2;
    short* w1h = (short*)w;       w += 256 * 256 * 2;
    short* w1l = (short*)w;       w += 256 * 256 * 2;
    short* w2h = (short*)w;       w += 128 * 256 * 2;
    short* w2l = (short*)w;       w += 128 * 256 * 2;

    short* xh = (short*)bufA;
    short* xl = xh + (size_t)n * 256;
    short* h1h = (short*)bufA;
    short* h1l = h1h + (size_t)n * 256;
    short* h3h = (short*)bufB;
    short* h3l = h3h + (size_t)n * 256;

    const int tb = 256;
    k_init<<<(n + tb - 1) / tb, tb, 0, stream>>>(cnt, cursor, counter, balance, n);
    k_count<<<(e + tb - 1) / tb, tb, 0, stream>>>(dst, cnt, e);
    k_allocdinv<<<(n + tb - 1) / tb, tb, 0, stream>>>(cnt, row_start, counter, dinv, n);
    k_fill<<<(e + tb - 1) / tb, tb, 0, stream>>>(src, dst, dinv, row_start, cursor,
                                                 csr_src, csr_norm, e);

    const int total8 = n * 32;
    k_splitfused<<<(total8 + 163840 + tb - 1) / tb, tb, 0, stream>>>(
        x, xh, xl, total8, W0, W1, W2, w0h, w0l, w1h, w1l, w2h, w2l);

    const int nbm = (n + 127) / 128;
    {
        int nwg = nbm * 2, q = nwg / 8, r = nwg % 8;
        k_gemm_bf16s<<<nwg, 256, 0, stream>>>(xh, xl, w0h, w0l, bufB, n, 256, 2, q, r);
        k_agg4<true, 1><<<(n + 3) / 4, 256, 0, stream>>>(bufB, dinv, csr_src, csr_norm,
                                                         row_start, cnt, b0, nullptr,
                                                         h1h, h1l, n);
        k_gemm_bf16s<<<nwg, 256, 0, stream>>>(h1h, h1l, w1h, w1l, bufB, n, 256, 2, q, r);
        k_agg4<true, 0><<<(n + 3) / 4, 256, 0, stream>>>(bufB, dinv, csr_src, csr_norm,
                                                         row_start, cnt, b1, bufA,
                                                         nullptr, nullptr, n);
    }

    dim3 gq(nbm, 4);
    k_quant10<<<gq, 256, 0, stream>>>(bufA, cent, h3h, h3l, balance, n);

    {
        int nwg = nbm, q = nwg / 8, r = nwg % 8;
        k_gemm_bf16s<<<nwg, 256, 0, stream>>>(h3h, h3l, w2h, w2l, bufA, n, 128, 1, q, r);
    }
    k_agg2<<<(n + 3) / 4, 256, 0, stream>>>(bufA, dinv, csr_src, csr_norm,
                                            row_start, cnt, b2, out, n);
    k_reg<<<1, 512, 0, stream>>>(balance, out + (size_t)n * 128, 1.0f / (float)n);
}

// Round 17
// 598.444 us; speedup vs baseline: 1.0219x; 1.0219x over previous
//
#include <hip/hip_runtime.h>
#include <math.h>

// ---------------------------------------------------------------------------
// GCN pipeline: conv1(relu) -> conv2(relu) -> quantize(+reg) -> add -> conv3
// GEMMs: split-bf16 MFMA (Ootomo 3-term), pre-split hi/lo tables, register
// prefetch + LDS-transposed epilogue, XCD-chunk-swizzled grid. Quantize:
// proven VALU register-GEMM quant4 (r16's single-barrier variant regressed:
// 4 blk/CU occupancy is load-bearing for the post-FMA softmax chains).
// ---------------------------------------------------------------------------

typedef short bf16x8 __attribute__((ext_vector_type(8)));
typedef float f32x4 __attribute__((ext_vector_type(4)));

__device__ __forceinline__ unsigned short bf16_rne(float a) {
    unsigned u = __builtin_bit_cast(unsigned, a);
    return (unsigned short)((u + 0x7FFFu + ((u >> 16) & 1u)) >> 16);
}
__device__ __forceinline__ float bf16_to_f(unsigned short h) {
    return __builtin_bit_cast(float, (unsigned)h << 16);
}
__device__ __forceinline__ void split4(const float* e, unsigned short* h, unsigned short* l) {
#pragma unroll
    for (int t = 0; t < 4; ++t) {
        h[t] = bf16_rne(e[t]);
        l[t] = bf16_rne(e[t] - bf16_to_f(h[t]));
    }
}

// ---------------- CSR build ----------------

__global__ void k_init(int* cnt, int* cursor, int* counter, float* balance, int n) {
    int i = blockIdx.x * blockDim.x + threadIdx.x;
    if (i < n) { cnt[i] = 0; cursor[i] = 0; }
    if (i < 480) balance[i] = 0.f;
    if (i == 0) *counter = 0;
}

__global__ void k_count(const int* __restrict__ dst, int* __restrict__ cnt, int e) {
    int i = blockIdx.x * blockDim.x + threadIdx.x;
    if (i < e) atomicAdd(&cnt[dst[i]], 1);
}

__global__ void k_allocdinv(const int* __restrict__ cnt, int* __restrict__ row_start,
                            int* __restrict__ counter, float* __restrict__ dinv, int n) {
    int i = blockIdx.x * blockDim.x + threadIdx.x;
    if (i < n) {
        row_start[i] = atomicAdd(counter, cnt[i]);
        dinv[i] = rsqrtf((float)cnt[i] + 1.0f);   // +1 self loop
    }
}

__global__ void k_fill(const int* __restrict__ src, const int* __restrict__ dst,
                       const float* __restrict__ dinv, const int* __restrict__ row_start,
                       int* __restrict__ cursor, int* __restrict__ csr_src,
                       float* __restrict__ csr_norm, int e) {
    int i = blockIdx.x * blockDim.x + threadIdx.x;
    if (i >= e) return;
    int s = src[i], d = dst[i];
    int slot = atomicAdd(&cursor[d], 1);
    int idx = row_start[d] + slot;
    csr_src[idx] = s;
    csr_norm[idx] = dinv[s] * dinv[d];
}

// ---------------- fused split kernel ----------------

__global__ void k_splitfused(const float* __restrict__ X, short* __restrict__ Xh,
                             short* __restrict__ Xl, int total8,
                             const float* __restrict__ W0, const float* __restrict__ W1,
                             const float* __restrict__ W2,
                             short* __restrict__ w0h, short* __restrict__ w0l,
                             short* __restrict__ w1h, short* __restrict__ w1l,
                             short* __restrict__ w2h, short* __restrict__ w2l) {
    int i = blockIdx.x * blockDim.x + threadIdx.x;
    if (i < total8) {
        float4 a = *(const float4*)(X + (size_t)i * 8);
        float4 b = *(const float4*)(X + (size_t)i * 8 + 4);
        float e0[4] = {a.x, a.y, a.z, a.w}, e1[4] = {b.x, b.y, b.z, b.w};
        unsigned short h0[4], l0[4], h1[4], l1[4];
        split4(e0, h0, l0);
        split4(e1, h1, l1);
        *(uint4*)(Xh + (size_t)i * 8) = make_uint4(h0[0] | (h0[1] << 16), h0[2] | (h0[3] << 16),
                                                  h1[0] | (h1[1] << 16), h1[2] | (h1[3] << 16));
        *(uint4*)(Xl + (size_t)i * 8) = make_uint4(l0[0] | (l0[1] << 16), l0[2] | (l0[3] << 16),
                                                  l1[0] | (l1[1] << 16), l1[2] | (l1[3] << 16));
        return;
    }
    int k = i - total8;
    if (k >= 163840) return;
    float v;
    short *ph, *pl;
    int j;
    if (k < 65536) {
        j = k; v = W0[(j & 255) * 256 + (j >> 8)]; ph = w0h; pl = w0l;
    } else if (k < 131072) {
        j = k - 65536; v = W1[(j & 255) * 256 + (j >> 8)]; ph = w1h; pl = w1l;
    } else {
        j = k - 131072; v = W2[(j & 255) * 128 + (j >> 8)]; ph = w2h; pl = w2l;
    }
    unsigned short h = bf16_rne(v);
    ph[j] = (short)h;
    pl[j] = (short)bf16_rne(v - bf16_to_f(h));
}

// ---------------- bf16-split MFMA GEMM (XCD-chunk swizzled) ----------------

__global__ __launch_bounds__(256, 2) void k_gemm_bf16s(const short* __restrict__ Ah,
                                                       const short* __restrict__ Al,
                                                       const short* __restrict__ Bh,
                                                       const short* __restrict__ Bl,
                                                       float* __restrict__ C,
                                                       int M, int N, int nbn,
                                                       int q, int r) {
    const int s = blockIdx.x;
    const int xcd = s & 7, jj = s >> 3;
    const int w = (xcd < r ? xcd * (q + 1) : r * (q + 1) + (xcd - r) * q) + jj;
    const int bm = (w / nbn) * 128;
    const int bn = (w % nbn) * 128;

    __shared__ short smem[4 * 128 * 56];
    short* Ash = smem;
    short* Asl = smem + 7168;
    short* Bsh = smem + 14336;
    short* Bsl = smem + 21504;
    const int tid = threadIdx.x;
    const int wave = tid >> 6, lane = tid & 63;
    const int wr = wave >> 1, wc = wave & 1;
    const int lr = lane & 15, lk = lane >> 4;

    int srow[2], ssg[2];
    bool aval[2];
#pragma unroll
    for (int it = 0; it < 2; ++it) {
        int u = it * 256 + tid;
        srow[it] = u >> 2;
        ssg[it] = (u & 3) << 3;
        aval[it] = (bm + srow[it]) < M;
    }

    const bf16x8 z8 = {0, 0, 0, 0, 0, 0, 0, 0};
    bf16x8 pah[2], pal[2], pbh[2], pbl[2];

    auto prefetch = [&](int k0) {
#pragma unroll
        for (int it = 0; it < 2; ++it) {
            size_t arow = (size_t)(bm + srow[it]) * 256 + k0 + ssg[it];
            size_t brow = (size_t)(bn + srow[it]) * 256 + k0 + ssg[it];
            pah[it] = aval[it] ? *(const bf16x8*)(Ah + arow) : z8;
            pal[it] = aval[it] ? *(const bf16x8*)(Al + arow) : z8;
            pbh[it] = *(const bf16x8*)(Bh + brow);
            pbl[it] = *(const bf16x8*)(Bl + brow);
        }
    };

    f32x4 acc[4][4] = {};
    prefetch(0);

    for (int k0 = 0; k0 < 256; k0 += 32) {
#pragma unroll
        for (int it = 0; it < 2; ++it) {
            int off = srow[it] * 56 + ssg[it];
            *(bf16x8*)&Ash[off] = pah[it];
            *(bf16x8*)&Asl[off] = pal[it];
            *(bf16x8*)&Bsh[off] = pbh[it];
            *(bf16x8*)&Bsl[off] = pbl[it];
        }
        __syncthreads();

        bf16x8 ah[4], al[4], bh[4], bl[4];
#pragma unroll
        for (int i = 0; i < 4; ++i) {
            int off = (wr * 64 + i * 16 + lr) * 56 + lk * 8;
            ah[i] = *(bf16x8*)&Ash[off];
            al[i] = *(bf16x8*)&Asl[off];
        }
#pragma unroll
        for (int j = 0; j < 4; ++j) {
            int off = (wc * 64 + j * 16 + lr) * 56 + lk * 8;
            bh[j] = *(bf16x8*)&Bsh[off];
            bl[j] = *(bf16x8*)&Bsl[off];
        }

        if (k0 < 224) prefetch(k0 + 32);   // issue next chunk under MFMA

#pragma unroll
        for (int i = 0; i < 4; ++i)
#pragma unroll
            for (int j = 0; j < 4; ++j) {
                acc[i][j] = __builtin_amdgcn_mfma_f32_16x16x32_bf16(al[i], bh[j], acc[i][j], 0, 0, 0);
                acc[i][j] = __builtin_amdgcn_mfma_f32_16x16x32_bf16(ah[i], bl[j], acc[i][j], 0, 0, 0);
                acc[i][j] = __builtin_amdgcn_mfma_f32_16x16x32_bf16(ah[i], bh[j], acc[i][j], 0, 0, 0);
            }
        __syncthreads();
    }

    // coalesced epilogue (C/D layout col=lane&15, row=(lane>>4)*4+reg [m89])
    float* Cs = (float*)smem;
#pragma unroll
    for (int p = 0; p < 2; ++p) {
        if (wc == p) {
#pragma unroll
            for (int i = 0; i < 4; ++i)
#pragma unroll
                for (int r2 = 0; r2 < 4; ++r2) {
                    int row = wr * 64 + i * 16 + lk * 4 + r2;
#pragma unroll
                    for (int j = 0; j < 4; ++j)
                        Cs[row * 68 + j * 16 + lr] = acc[i][j][r2];
                }
        }
        __syncthreads();
#pragma unroll
        for (int t = 0; t < 8; ++t) {
            int idx = t * 256 + tid;
            int row = idx >> 4, c4 = idx & 15;
            if (bm + row < M)
                *(float4*)(C + (size_t)(bm + row) * N + bn + p * 64 + c4 * 4) =
                    *(const float4*)&Cs[row * 68 + c4 * 4];
        }
        __syncthreads();
    }
}

// ---------------- Aggregation (gather over CSR), one wave per node ----------------
// L3-BW-bound floor ~125us (rounds 4-6: 3.7 TB/s, FETCH = 8 XCD x 51 MB,
// invariant across 3 MLP structures). MODE=1 emits bf16 hi/lo split.

template <bool RELU, int MODE>
__global__ __launch_bounds__(256, 4) void k_agg4(const float* __restrict__ xw,
                                                 const float* __restrict__ dinv,
                                                 const int* __restrict__ csr_src,
                                                 const float* __restrict__ csr_norm,
                                                 const int* __restrict__ row_start,
                                                 const int* __restrict__ cnt,
                                                 const float* __restrict__ bias,
                                                 float* __restrict__ out,
                                                 short* __restrict__ outH,
                                                 short* __restrict__ outL, int n) {
    int node = blockIdx.x * 4 + (threadIdx.x >> 6);
    if (node >= n) return;
    int lane = threadIdx.x & 63;
    int c = lane * 4;
    float di = dinv[node];
    float4 self = *(const float4*)(xw + (size_t)node * 256 + c);
    float4 bv = *(const float4*)(bias + c);
    float sw = di * di;
    float ax = self.x * sw + bv.x;
    float ay = self.y * sw + bv.y;
    float az = self.z * sw + bv.z;
    float aw = self.w * sw + bv.w;
    int st = row_start[node];
    int m = cnt[node];
    for (int t0 = 0; t0 < m; t0 += 64) {
        int rem = m - t0;
        int cnt_i = rem < 64 ? rem : 64;
        int idx_l = 0;
        float nrm_l = 0.f;
        if (lane < cnt_i) {
            idx_l = csr_src[st + t0 + lane];
            nrm_l = csr_norm[st + t0 + lane];
        }
        int t = 0;
        for (; t + 8 <= cnt_i; t += 8) {
            const float* p0 = xw + (size_t)__shfl(idx_l, t + 0, 64) * 256 + c;
            const float* p1 = xw + (size_t)__shfl(idx_l, t + 1, 64) * 256 + c;
            const float* p2 = xw + (size_t)__shfl(idx_l, t + 2, 64) * 256 + c;
            const float* p3 = xw + (size_t)__shfl(idx_l, t + 3, 64) * 256 + c;
            const float* p4 = xw + (size_t)__shfl(idx_l, t + 4, 64) * 256 + c;
            const float* p5 = xw + (size_t)__shfl(idx_l, t + 5, 64) * 256 + c;
            const float* p6 = xw + (size_t)__shfl(idx_l, t + 6, 64) * 256 + c;
            const float* p7 = xw + (size_t)__shfl(idx_l, t + 7, 64) * 256 + c;
            float4 v0 = *(const float4*)p0;
            float4 v1 = *(const float4*)p1;
            float4 v2 = *(const float4*)p2;
            float4 v3 = *(const float4*)p3;
            float4 v4 = *(const float4*)p4;
            float4 v5 = *(const float4*)p5;
            float4 v6 = *(const float4*)p6;
            float4 v7 = *(const float4*)p7;
            float w0 = __shfl(nrm_l, t + 0, 64);
            float w1 = __shfl(nrm_l, t + 1, 64);
            float w2 = __shfl(nrm_l, t + 2, 64);
            float w3 = __shfl(nrm_l, t + 3, 64);
            float w4 = __shfl(nrm_l, t + 4, 64);
            float w5 = __shfl(nrm_l, t + 5, 64);
            float w6 = __shfl(nrm_l, t + 6, 64);
            float w7 = __shfl(nrm_l, t + 7, 64);
            ax += v0.x * w0; ay += v0.y * w0; az += v0.z * w0; aw += v0.w * w0;
            ax += v1.x * w1; ay += v1.y * w1; az += v1.z * w1; aw += v1.w * w1;
            ax += v2.x * w2; ay += v2.y * w2; az += v2.z * w2; aw += v2.w * w2;
            ax += v3.x * w3; ay += v3.y * w3; az += v3.z * w3; aw += v3.w * w3;
            ax += v4.x * w4; ay += v4.y * w4; az += v4.z * w4; aw += v4.w * w4;
            ax += v5.x * w5; ay += v5.y * w5; az += v5.z * w5; aw += v5.w * w5;
            ax += v6.x * w6; ay += v6.y * w6; az += v6.z * w6; aw += v6.w * w6;
            ax += v7.x * w7; ay += v7.y * w7; az += v7.z * w7; aw += v7.w * w7;
        }
        for (; t < cnt_i; ++t) {
            int s = __shfl(idx_l, t, 64);
            float w = __shfl(nrm_l, t, 64);
            float4 v = *(const float4*)(xw + (size_t)s * 256 + c);
            ax += v.x * w; ay += v.y * w; az += v.z * w; aw += v.w * w;
        }
    }
    if (RELU) {
        ax = ax > 0.f ? ax : 0.5f * ax;
        ay = ay > 0.f ? ay : 0.5f * ay;
        az = az > 0.f ? az : 0.5f * az;
        aw = aw > 0.f ? aw : 0.5f * aw;
    }
    if (MODE == 0) {
        *(float4*)(out + (size_t)node * 256 + c) = make_float4(ax, ay, az, aw);
    } else {
        float e[4] = {ax, ay, az, aw};
        unsigned short h[4], l[4];
        split4(e, h, l);
        size_t o = (size_t)node * 256 + c;
        *(uint2*)(outH + o) = make_uint2(h[0] | (h[1] << 16), h[2] | (h[3] << 16));
        *(uint2*)(outL + o) = make_uint2(l[0] | (l[1] << 16), l[2] | (l[3] << 16));
    }
}

__global__ __launch_bounds__(256, 4) void k_agg2(const float* __restrict__ xw,
                                                 const float* __restrict__ dinv,
                                                 const int* __restrict__ csr_src,
                                                 const float* __restrict__ csr_norm,
                                                 const int* __restrict__ row_start,
                                                 const int* __restrict__ cnt,
                                                 const float* __restrict__ bias,
                                                 float* __restrict__ out, int n) {
    int node = blockIdx.x * 4 + (threadIdx.x >> 6);
    if (node >= n) return;
    int lane = threadIdx.x & 63;
    int c = lane * 2;
    float di = dinv[node];
    float2 self = *(const float2*)(xw + (size_t)node * 128 + c);
    float2 bv = *(const float2*)(bias + c);
    float sw = di * di;
    float ax = self.x * sw + bv.x;
    float ay = self.y * sw + bv.y;
    int st = row_start[node];
    int m = cnt[node];
    for (int t0 = 0; t0 < m; t0 += 64) {
        int rem = m - t0;
        int cnt_i = rem < 64 ? rem : 64;
        int idx_l = 0;
        float nrm_l = 0.f;
        if (lane < cnt_i) {
            idx_l = csr_src[st + t0 + lane];
            nrm_l = csr_norm[st + t0 + lane];
        }
        int t = 0;
        for (; t + 8 <= cnt_i; t += 8) {
            const float* p0 = xw + (size_t)__shfl(idx_l, t + 0, 64) * 128 + c;
            const float* p1 = xw + (size_t)__shfl(idx_l, t + 1, 64) * 128 + c;
            const float* p2 = xw + (size_t)__shfl(idx_l, t + 2, 64) * 128 + c;
            const float* p3 = xw + (size_t)__shfl(idx_l, t + 3, 64) * 128 + c;
            const float* p4 = xw + (size_t)__shfl(idx_l, t + 4, 64) * 128 + c;
            const float* p5 = xw + (size_t)__shfl(idx_l, t + 5, 64) * 128 + c;
            const float* p6 = xw + (size_t)__shfl(idx_l, t + 6, 64) * 128 + c;
            const float* p7 = xw + (size_t)__shfl(idx_l, t + 7, 64) * 128 + c;
            float2 v0 = *(const float2*)p0;
            float2 v1 = *(const float2*)p1;
            float2 v2 = *(const float2*)p2;
            float2 v3 = *(const float2*)p3;
            float2 v4 = *(const float2*)p4;
            float2 v5 = *(const float2*)p5;
            float2 v6 = *(const float2*)p6;
            float2 v7 = *(const float2*)p7;
            float w0 = __shfl(nrm_l, t + 0, 64);
            float w1 = __shfl(nrm_l, t + 1, 64);
            float w2 = __shfl(nrm_l, t + 2, 64);
            float w3 = __shfl(nrm_l, t + 3, 64);
            float w4 = __shfl(nrm_l, t + 4, 64);
            float w5 = __shfl(nrm_l, t + 5, 64);
            float w6 = __shfl(nrm_l, t + 6, 64);
            float w7 = __shfl(nrm_l, t + 7, 64);
            ax += v0.x * w0; ay += v0.y * w0;
            ax += v1.x * w1; ay += v1.y * w1;
            ax += v2.x * w2; ay += v2.y * w2;
            ax += v3.x * w3; ay += v3.y * w3;
            ax += v4.x * w4; ay += v4.y * w4;
            ax += v5.x * w5; ay += v5.y * w5;
            ax += v6.x * w6; ay += v6.y * w6;
            ax += v7.x * w7; ay += v7.y * w7;
        }
        for (; t < cnt_i; ++t) {
            int s = __shfl(idx_l, t, 64);
            float w = __shfl(nrm_l, t, 64);
            float2 v = *(const float2*)(xw + (size_t)s * 128 + c);
            ax += v.x * w; ay += v.y * w;
        }
    }
    *(float2*)(out + (size_t)node * 128 + c) = make_float2(ax, ay);
}

// ---------------- Quantize (VALU register GEMM + reg softmax, proven) ----

__global__ __launch_bounds__(256, 4) void k_quant4(const float* __restrict__ h2,
                                                   const float* __restrict__ cent,
                                                   short* __restrict__ h3h,
                                                   short* __restrict__ h3l,
                                                   float* __restrict__ balance_g, int n) {
    __shared__ float As[32 * 132];     // As[k][node]
    __shared__ float Bs[32 * 132];     // Bs[k][swizzled cent col]
    __shared__ float bal4[4 * 128];
    __shared__ int km_ls[128 * 4];
    const int tid = threadIdx.x;
    const int n0 = blockIdx.x * 128;
    const int d = blockIdx.y;
    const int ty = tid >> 4, tx = tid & 15;
    const int wave = tid >> 6, lane = tid & 63;

    int gid, base, sz;
    if (tx == 0)       { gid = 0; base = 0;  sz = 1; }
    else if (tx <= 2)  { gid = 1; base = 1;  sz = 2; }
    else if (tx <= 6)  { gid = 2; base = 3;  sz = 4; }
    else if (tx <= 14) { gid = 3; base = 7;  sz = 8; }
    else               { gid = 0; base = 15; sz = 0; }
    const int l = tx - base;
    const int segbase = lane & 48;

    {
        int k = tid >> 3, r = tid & 7;
        int col = (r < 4) ? (60 + r) : (120 + r);
        Bs[k * 132 + col] = 0.f;
    }

    const int srow = tid >> 3, sk4 = tid & 7;
    float acc[8][8] = {};

    // ---- stage chunk 1 (c0=0) ----
#pragma unroll
    for (int it = 0; it < 4; ++it) {
        int row = srow + it * 32;
        float4 v = make_float4(0.f, 0.f, 0.f, 0.f);
        if (n0 + row < n)
            v = *(const float4*)(h2 + (size_t)(n0 + row) * 256 + d * 64 + sk4 * 4);
        As[(sk4 * 4 + 0) * 132 + row] = v.x;
        As[(sk4 * 4 + 1) * 132 + row] = v.y;
        As[(sk4 * 4 + 2) * 132 + row] = v.z;
        As[(sk4 * 4 + 3) * 132 + row] = v.w;
    }
#pragma unroll
    for (int it = 0; it < 4; ++it) {
        int q = it * 256 + tid;
        if (q < 960) {
            int cc = q >> 3, k4 = q & 7;
            float4 v = *(const float4*)(cent + (size_t)cc * 256 + d * 64 + k4 * 4);
            int col = ((cc >> 3) << 2) + (((cc >> 2) & 1) << 6) + (cc & 3);
            Bs[(k4 * 4 + 0) * 132 + col] = v.x;
            Bs[(k4 * 4 + 1) * 132 + col] = v.y;
            Bs[(k4 * 4 + 2) * 132 + col] = v.z;
            Bs[(k4 * 4 + 3) * 132 + col] = v.w;
        }
    }
    // prefetch chunk-2 h2 into regs (issue-early; lands under chunk-1 FMA)
    float4 ph[4];
#pragma unroll
    for (int it = 0; it < 4; ++it) {
        int row = srow + it * 32;
        ph[it] = make_float4(0.f, 0.f, 0.f, 0.f);
        if (n0 + row < n)
            ph[it] = *(const float4*)(h2 + (size_t)(n0 + row) * 256 + d * 64 + 32 + sk4 * 4);
    }
    __syncthreads();

    // ---- FMA chunk 1 ----
#pragma unroll 4
    for (int k = 0; k < 32; ++k) {
        float4 a0 = *(const float4*)&As[k * 132 + ty * 8];
        float4 a1 = *(const float4*)&As[k * 132 + ty * 8 + 4];
        float4 b0 = *(const float4*)&Bs[k * 132 + tx * 4];
        float4 b1 = *(const float4*)&Bs[k * 132 + 64 + tx * 4];
        float av[8] = {a0.x, a0.y, a0.z, a0.w, a1.x, a1.y, a1.z, a1.w};
        float bv[8] = {b0.x, b0.y, b0.z, b0.w, b1.x, b1.y, b1.z, b1.w};
#pragma unroll
        for (int i = 0; i < 8; ++i)
#pragma unroll
            for (int j = 0; j < 8; ++j)
                acc[i][j] += av[i] * bv[j];
    }
    __syncthreads();

    // ---- stage chunk 2 (h from regs, cent fresh) ----
#pragma unroll
    for (int it = 0; it < 4; ++it) {
        int row = srow + it * 32;
        As[(sk4 * 4 + 0) * 132 + row] = ph[it].x;
        As[(sk4 * 4 + 1) * 132 + row] = ph[it].y;
        As[(sk4 * 4 + 2) * 132 + row] = ph[it].z;
        As[(sk4 * 4 + 3) * 132 + row] = ph[it].w;
    }
#pragma unroll
    for (int it = 0; it < 4; ++it) {
        int q = it * 256 + tid;
        if (q < 960) {
            int cc = q >> 3, k4 = q & 7;
            float4 v = *(const float4*)(cent + (size_t)cc * 256 + d * 64 + 32 + k4 * 4);
            int col = ((cc >> 3) << 2) + (((cc >> 2) & 1) << 6) + (cc & 3);
            Bs[(k4 * 4 + 0) * 132 + col] = v.x;
            Bs[(k4 * 4 + 1) * 132 + col] = v.y;
            Bs[(k4 * 4 + 2) * 132 + col] = v.z;
            Bs[(k4 * 4 + 3) * 132 + col] = v.w;
        }
    }
    __syncthreads();

    // ---- FMA chunk 2 ----
#pragma unroll 4
    for (int k = 0; k < 32; ++k) {
        float4 a0 = *(const float4*)&As[k * 132 + ty * 8];
        float4 a1 = *(const float4*)&As[k * 132 + ty * 8 + 4];
        float4 b0 = *(const float4*)&Bs[k * 132 + tx * 4];
        float4 b1 = *(const float4*)&Bs[k * 132 + 64 + tx * 4];
        float av[8] = {a0.x, a0.y, a0.z, a0.w, a1.x, a1.y, a1.z, a1.w};
        float bv[8] = {b0.x, b0.y, b0.z, b0.w, b1.x, b1.y, b1.z, b1.w};
#pragma unroll
        for (int i = 0; i < 8; ++i)
#pragma unroll
            for (int j = 0; j < 8; ++j)
                acc[i][j] += av[i] * bv[j];
    }

    // ---- per-group softmax/argmax/balance in registers ----
    float balp[8] = {};
#pragma unroll
    for (int i = 0; i < 8; ++i) {
        const int node = ty * 8 + i;
        const bool act = (n0 + node) < n;
        float m = acc[i][0];
        int am = tx * 8;
#pragma unroll
        for (int j = 1; j < 8; ++j)
            if (acc[i][j] > m) { m = acc[i][j]; am = tx * 8 + j; }
#pragma unroll
        for (int s = 1; s <= 4; s <<= 1) {
            int pl = l ^ s;
            int srcl = segbase + base + pl;
            float mo = __shfl(m, srcl, 64);
            int amo = __shfl(am, srcl, 64);
            if (pl < sz && (mo > m || (mo == m && amo < am))) { m = mo; am = amo; }
        }
        float Z = 0.f;
#pragma unroll
        for (int j = 0; j < 8; ++j) {
            float e2 = expf(acc[i][j] - m);
            acc[i][j] = e2;
            Z += e2;
        }
#pragma unroll
        for (int s = 1; s <= 4; s <<= 1) {
            int pl = l ^ s;
            int srcl = segbase + base + pl;
            float Zo = __shfl(Z, srcl, 64);
            if (pl < sz) Z += Zo;
        }
        float invZ = (act && sz > 0) ? (1.0f / Z) : 0.f;
#pragma unroll
        for (int j = 0; j < 8; ++j) balp[j] += acc[i][j] * invZ;
        if (l == 0 && sz > 0) km_ls[node * 4 + gid] = am;
    }

#pragma unroll
    for (int j = 0; j < 8; ++j) {
        float v = balp[j];
        v += __shfl_xor(v, 16, 64);
        v += __shfl_xor(v, 32, 64);
        balp[j] = v;
    }
    if (lane < 16) {
#pragma unroll
        for (int j = 0; j < 8; ++j)
            bal4[wave * 128 + tx * 8 + j] = balp[j];
    }
    __syncthreads();
    if (tid < 120) {
        float s = bal4[tid] + bal4[128 + tid] + bal4[256 + tid] + bal4[384 + tid];
        atomicAdd(&balance_g[tid * 4 + d], s);
    }

    // ---- P4: h3 = h2 + max_j cent[km_j], bf16 hi/lo emission ----
    {
        const int node = tid >> 1;
        const int half = tid & 1;
        if (n0 + node < n) {
            int k0 = km_ls[node * 4 + 0], k1 = km_ls[node * 4 + 1];
            int k2 = km_ls[node * 4 + 2], k3 = km_ls[node * 4 + 3];
            const float* hp = h2 + (size_t)(n0 + node) * 256 + d * 64 + half * 32;
            const float* c0 = cent + (size_t)k0 * 256 + d * 64 + half * 32;
            const float* c1 = cent + (size_t)k1 * 256 + d * 64 + half * 32;
            const float* c2 = cent + (size_t)k2 * 256 + d * 64 + half * 32;
            const float* c3 = cent + (size_t)k3 * 256 + d * 64 + half * 32;
            size_t obase = (size_t)(n0 + node) * 256 + d * 64 + half * 32;
#pragma unroll
            for (int q = 0; q < 8; ++q) {
                int g = q * 4;
                float4 hv = *(const float4*)(hp + g);
                float4 v0 = *(const float4*)(c0 + g);
                float4 v1 = *(const float4*)(c1 + g);
                float4 v2 = *(const float4*)(c2 + g);
                float4 v3 = *(const float4*)(c3 + g);
                float e[4];
                e[0] = hv.x + fmaxf(fmaxf(v0.x, v1.x), fmaxf(v2.x, v3.x));
                e[1] = hv.y + fmaxf(fmaxf(v0.y, v1.y), fmaxf(v2.y, v3.y));
                e[2] = hv.z + fmaxf(fmaxf(v0.z, v1.z), fmaxf(v2.z, v3.z));
                e[3] = hv.w + fmaxf(fmaxf(v0.w, v1.w), fmaxf(v2.w, v3.w));
                unsigned short h[4], l2[4];
                split4(e, h, l2);
                *(uint2*)(h3h + obase + g) = make_uint2(h[0] | (h[1] << 16), h[2] | (h[3] << 16));
                *(uint2*)(h3l + obase + g) = make_uint2(l2[0] | (l2[1] << 16), l2[2] | (l2[3] << 16));
            }
        }
    }
}

__global__ void k_reg(const float* __restrict__ balance_g, float* __restrict__ out_reg,
                      float inv_n) {
    __shared__ float red[512];
    int tid = threadIdx.x;
    float v = 0.f;
    if (tid < 480) {
        int k = tid >> 2;
        float target = (k < 8) ? 0.125f : (k < 24) ? 0.0625f : (k < 56) ? 0.03125f : 0.015625f;
        float b = balance_g[tid] * inv_n;
        float df = b - target;
        v = df * df;
    }
    red[tid] = v;
    __syncthreads();
    for (int s = 256; s > 0; s >>= 1) {
        if (tid < s) red[tid] += red[tid + s];
        __syncthreads();
    }
    if (tid == 0) *out_reg = sqrtf(red[0]);
}

// ---------------- host launch ----------------

extern "C" void kernel_launch(void* const* d_in, const int* in_sizes, int n_in,
                              void* d_out, int out_size, void* d_ws, size_t ws_size,
                              hipStream_t stream) {
    const float* x    = (const float*)d_in[0];
    const int*   ei   = (const int*)d_in[1];
    const float* W0   = (const float*)d_in[2];
    const float* b0   = (const float*)d_in[3];
    const float* W1   = (const float*)d_in[4];
    const float* b1   = (const float*)d_in[5];
    const float* W2   = (const float*)d_in[6];
    const float* b2   = (const float*)d_in[7];
    const float* cent = (const float*)d_in[8];
    const int n = in_sizes[0] / 256;
    const int e = in_sizes[1] / 2;
    const int* src = ei;
    const int* dst = ei + e;
    float* out = (float*)d_out;

    char* w = (char*)d_ws;
    float* bufA = (float*)w;      w += (size_t)n * 256 * 4;
    float* bufB = (float*)w;      w += (size_t)n * 256 * 4;
    float* dinv = (float*)w;      w += (size_t)n * 4;
    int* cnt = (int*)w;           w += (size_t)n * 4;
    int* row_start = (int*)w;     w += (size_t)n * 4;
    int* cursor = (int*)w;        w += (size_t)n * 4;
    int* csr_src = (int*)w;       w += (size_t)e * 4;
    float* csr_norm = (float*)w;  w += (size_t)e * 4;
    int* counter = (int*)w;       w += 256;
    float* balance = (float*)w;   w += 480 * 4;
    short* w0h = (short*)w;       w += 256 * 256 * 2;
    short* w0l = (short*)w;       w += 256 * 256 * 2;
    short* w1h = (short*)w;       w += 256 * 256 * 2;
    short* w1l = (short*)w;       w += 256 * 256 * 2;
    short* w2h = (short*)w;       w += 128 * 256 * 2;
    short* w2l = (short*)w;       w += 128 * 256 * 2;

    short* xh = (short*)bufA;
    short* xl = xh + (size_t)n * 256;
    short* h1h = (short*)bufA;
    short* h1l = h1h + (size_t)n * 256;
    short* h3h = (short*)bufB;
    short* h3l = h3h + (size_t)n * 256;

    const int tb = 256;
    k_init<<<(n + tb - 1) / tb, tb, 0, stream>>>(cnt, cursor, counter, balance, n);
    k_count<<<(e + tb - 1) / tb, tb, 0, stream>>>(dst, cnt, e);
    k_allocdinv<<<(n + tb - 1) / tb, tb, 0, stream>>>(cnt, row_start, counter, dinv, n);
    k_fill<<<(e + tb - 1) / tb, tb, 0, stream>>>(src, dst, dinv, row_start, cursor,
                                                 csr_src, csr_norm, e);

    const int total8 = n * 32;
    k_splitfused<<<(total8 + 163840 + tb - 1) / tb, tb, 0, stream>>>(
        x, xh, xl, total8, W0, W1, W2, w0h, w0l, w1h, w1l, w2h, w2l);

    const int nbm = (n + 127) / 128;
    {
        int nwg = nbm * 2, q = nwg / 8, r = nwg % 8;
        k_gemm_bf16s<<<nwg, 256, 0, stream>>>(xh, xl, w0h, w0l, bufB, n, 256, 2, q, r);
        k_agg4<true, 1><<<(n + 3) / 4, 256, 0, stream>>>(bufB, dinv, csr_src, csr_norm,
                                                         row_start, cnt, b0, nullptr,
                                                         h1h, h1l, n);
        k_gemm_bf16s<<<nwg, 256, 0, stream>>>(h1h, h1l, w1h, w1l, bufB, n, 256, 2, q, r);
        k_agg4<true, 0><<<(n + 3) / 4, 256, 0, stream>>>(bufB, dinv, csr_src, csr_norm,
                                                         row_start, cnt, b1, bufA,
                                                         nullptr, nullptr, n);
    }

    dim3 gq(nbm, 4);
    k_quant4<<<gq, 256, 0, stream>>>(bufA, cent, h3h, h3l, balance, n);

    {
        int nwg = nbm, q = nwg / 8, r = nwg % 8;
        k_gemm_bf16s<<<nwg, 256, 0, stream>>>(h3h, h3l, w2h, w2l, bufA, n, 128, 1, q, r);
    }
    k_agg2<<<(n + 3) / 4, 256, 0, stream>>>(bufA, dinv, csr_src, csr_norm,
                                            row_start, cnt, b2, out, n);
    k_reg<<<1, 512, 0, stream>>>(balance, out + (size_t)n * 128, 1.0f / (float)n);
}